// Round 9
// baseline (27.369 us; speedup 1.0000x reference)
//
#include <hip/hip_runtime.h>
#include <stdint.h>

#define K_DIM 4096
#define KW 1024          // packed words per m-row
#define M_DIM 11008
#define B_DIM 16
#define GROUP_ROWS 2752  // M / 4 groups
#define QTR_W 256
#define NTILES 688       // M / 16

typedef int v4i __attribute__((ext_vector_type(4)));

// spread low byte p (4x 2-bit fields) into 4 bytes: {p&3,(p>>2)&3,(p>>4)&3,(p>>6)&3}
__device__ __forceinline__ int spread2(int p) {
    int t = p | (p << 12);
    return (t & 0x00030003) | (((t >> 2) & 0x00030003) << 8);
}

// ---------------- kernel 1: per-row activation quantization ----------------
// 64 blocks x 256 thr: block g -> row b=g>>2, quarter qt=g&3. Full-row absmax
// (redundant, L2-hot), quantize own quarter. Partial sums to sumq_part[b][qt].
__global__ __launch_bounds__(256) void quant_k(const float* __restrict__ in,
                                               int* __restrict__ qg,
                                               int* __restrict__ sumq_part,
                                               float* __restrict__ invs) {
    const int g = blockIdx.x, b = g >> 2, qt = g & 3;
    const int t = threadIdx.x, lane = t & 63, wid = t >> 6;

    const float4* row = (const float4*)(in + (size_t)b * K_DIM);
    float4 v[4];
#pragma unroll
    for (int i = 0; i < 4; ++i) v[i] = row[t + i * 256];

    float mx = 0.f;
#pragma unroll
    for (int i = 0; i < 4; ++i) {
        mx = fmaxf(mx, fabsf(v[i].x)); mx = fmaxf(mx, fabsf(v[i].y));
        mx = fmaxf(mx, fabsf(v[i].z)); mx = fmaxf(mx, fabsf(v[i].w));
    }
#pragma unroll
    for (int s = 1; s < 64; s <<= 1) mx = fmaxf(mx, __shfl_xor(mx, s, 64));

    __shared__ float wmax[4];
    __shared__ int wsum[4];
    if (lane == 0) wmax[wid] = mx;
    __syncthreads();
    const float bm = fmaxf(fmaxf(wmax[0], wmax[1]), fmaxf(wmax[2], wmax[3]));
    const float sc = 127.f / fmaxf(bm, 1e-5f);

    const float4 mine = v[qt];  // thread t quantizes word qt*256 + t
    float xs[4] = {mine.x, mine.y, mine.z, mine.w};
    int w = 0, ss = 0;
#pragma unroll
    for (int j = 0; j < 4; ++j) {
        int q = (int)rintf(xs[j] * sc);   // round-half-even, matches jnp.round
        q = q > 127 ? 127 : (q < -128 ? -128 : q);
        ss += q;
        w |= (q & 255) << (8 * j);
    }
    qg[b * KW + qt * QTR_W + t] = w;

#pragma unroll
    for (int s = 1; s < 64; s <<= 1) ss += __shfl_xor(ss, s, 64);
    if (lane == 0) wsum[wid] = ss;
    __syncthreads();
    if (t == 0) {
        sumq_part[b * 4 + qt] = wsum[0] + wsum[1] + wsum[2] + wsum[3];
        if (qt == 0) invs[b] = fmaxf(bm, 1e-5f) / 127.f;
    }
}

// ---------------- kernel 2: ternary GEMM partials, high occupancy ----------------
// 1376 blocks x 256 thr (4 waves) -> ~5.4 blocks/CU, ~21.5 waves/CU (2.7x R8).
// Block (tile, kh): 16 m-rows, K-half kh. Wave wid owns 512 k (8 MFMA steps).
// B-fragments load DIRECTLY global->VGPR (lane m = lane&15, k-slice (lane>>4)*16
// — same index math as the validated LDS path, minus the LDS). No NT hint.
// Writes integer partials; finalize_k combines.
__global__ __launch_bounds__(256, 5) void gemm_k(const int* __restrict__ wp,
                                                 const int* __restrict__ qg,
                                                 int* __restrict__ part) {
    __shared__ int red[4 * 64 * 4];  // 4 KB only -> occupancy not LDS-limited
    const int t = threadIdx.x, lane = t & 63, wid = t >> 6;
    const int bid = blockIdx.x;
    const int tile = bid >> 1, kh = bid & 1;
    const int m0 = tile * 16;
    const int lrow = lane & 15;   // b for A-frag, m-offset for B-frag
    const int lgrp = lane >> 4;   // k-group within the 64-k MFMA step
    const int koff = kh * 512 + wid * 128;  // this wave's k-word window (512 k)

    const int* qb = qg + lrow * KW + koff + lgrp * 4;
    const int* wb = wp + (size_t)(m0 + lrow) * KW + koff + lgrp * 4;

    // q fragments (L2-hot)
    v4i qr[8];
#pragma unroll
    for (int s = 0; s < 8; ++s) qr[s] = *(const v4i*)(qb + s * 16);

    v4i acc = {0, 0, 0, 0};
#pragma unroll
    for (int s = 0; s < 8; ++s) {
        v4i wv = *(const v4i*)(wb + s * 16);
        v4i bb;
        bb[0] = spread2(wv[0]); bb[1] = spread2(wv[1]);
        bb[2] = spread2(wv[2]); bb[3] = spread2(wv[3]);
        acc = __builtin_amdgcn_mfma_i32_16x16x64_i8(qr[s], bb, acc, 0, 0, 0);
    }

    // cross-wave reduce
    *(v4i*)(red + (wid * 64 + lane) * 4) = acc;
    __syncthreads();
    if (t < 256) {
        const int b = t >> 4, m = t & 15;
        const int src_lane = ((b >> 2) << 4) | m;  // D: col=lane&15, row=(lane>>4)*4+reg
        const int reg = b & 3;
        int sum = red[(0 * 64 + src_lane) * 4 + reg] + red[(1 * 64 + src_lane) * 4 + reg] +
                  red[(2 * 64 + src_lane) * 4 + reg] + red[(3 * 64 + src_lane) * 4 + reg];
        part[bid * 256 + t] = sum;   // [tile][kh][b][m]
    }
}

// ---------------- kernel 3: combine K-half partials + scale ----------------
__global__ __launch_bounds__(1024) void finalize_k(const int* __restrict__ part,
                                                   const int* __restrict__ sumq_part,
                                                   const float* __restrict__ invs,
                                                   const float* __restrict__ wscale,
                                                   float* __restrict__ out) {
    const int tg = blockIdx.x * 1024 + threadIdx.x;
    const int tile = tg >> 8, idx = tg & 255;
    const int b = idx >> 4, m = idx & 15;
    const int sum = part[tile * 512 + idx] + part[tile * 512 + 256 + idx];
    const int sq = sumq_part[b * 4 + 0] + sumq_part[b * 4 + 1] +
                   sumq_part[b * 4 + 2] + sumq_part[b * 4 + 3];
    const float val = (float)(sum - sq) * invs[b] * wscale[(tile * 16) / GROUP_ROWS];
    out[(size_t)b * M_DIM + tile * 16 + m] = val;
}

extern "C" void kernel_launch(void* const* d_in, const int* in_sizes, int n_in,
                              void* d_out, int out_size, void* d_ws, size_t ws_size,
                              hipStream_t stream) {
    const float* inp    = (const float*)d_in[0];
    const int*   wp     = (const int*)d_in[1];
    const float* wscale = (const float*)d_in[2];
    float* out = (float*)d_out;

    int*   qg   = (int*)d_ws;                  // 16384 words = 64 KB
    int*   sqp  = qg + B_DIM * KW;             // 64 ints
    float* invs = (float*)(sqp + B_DIM * 4);   // 16 floats
    int*   part = (int*)(invs + B_DIM);        // 1376*256 ints = 1.38 MB

    quant_k<<<dim3(B_DIM * 4), dim3(256), 0, stream>>>(inp, qg, sqp, invs);
    gemm_k<<<dim3(NTILES * 2), dim3(256), 0, stream>>>(wp, qg, part);
    finalize_k<<<dim3((NTILES * 256) / 1024), dim3(1024), 0, stream>>>(part, sqp, invs, wscale, out);
}